// Round 1
// baseline (352.336 us; speedup 1.0000x reference)
//
#include <hip/hip_runtime.h>
#include <math.h>

// Problem constants (from reference): peak_map [256, 131072] f32, scalar logit_thresh.
// Outputs concatenated: smooth_peaks [256*131072] f32, peak_mask [256*131072] f32 (0/1).
#define ROWS 256
#define COLS 131072
#define SHARP 10.0f

// Each thread handles 4 contiguous elements of one row.
// Threads per row = COLS/4 = 32768 = 2^15.
__global__ __launch_bounds__(256) void peak_extract_kernel(
    const float* __restrict__ x,
    const float* __restrict__ logit_thresh,
    float* __restrict__ smooth,
    float* __restrict__ mask)
{
    const float thresh = 1.0f / (1.0f + expf(-logit_thresh[0]));

    const long long gid  = (long long)blockIdx.x * blockDim.x + threadIdx.x;
    const int row  = (int)(gid >> 15);          // 2^15 threads per row
    const int col  = ((int)gid & 32767) << 2;   // element index within row

    const float* __restrict__ xr = x + (long long)row * COLS;

    // window needs elements [col-2, col+5]; v[k] = xr[col-2+k] with edge clamp
    float v[8];
    const float4 cur = *(const float4*)(xr + col);
    v[2] = cur.x; v[3] = cur.y; v[4] = cur.z; v[5] = cur.w;
    v[0] = xr[max(col - 2, 0)];
    v[1] = xr[max(col - 1, 0)];
    v[6] = xr[min(col + 4, COLS - 1)];
    v[7] = xr[min(col + 5, COLS - 1)];

    float s_out[4], m_out[4];
#pragma unroll
    for (int k = 0; k < 4; ++k) {
        // pooled = max over window of 5 centered at element k (v[k..k+4])
        float p = v[k];
        p = fmaxf(p, v[k + 1]);
        p = fmaxf(p, v[k + 2]);
        p = fmaxf(p, v[k + 3]);
        p = fmaxf(p, v[k + 4]);
        const float xv   = v[k + 2];
        const float gate = 1.0f / (1.0f + expf(-SHARP * (xv - thresh)));
        const float lm   = 1.0f / (1.0f + expf(-SHARP * (xv - p)));
        const float s    = xv * gate * lm;
        s_out[k] = s;
        m_out[k] = (s >= thresh) ? 1.0f : 0.0f;
    }

    const long long base = (long long)row * COLS + col;
    *(float4*)(smooth + base) = make_float4(s_out[0], s_out[1], s_out[2], s_out[3]);
    *(float4*)(mask   + base) = make_float4(m_out[0], m_out[1], m_out[2], m_out[3]);
}

extern "C" void kernel_launch(void* const* d_in, const int* in_sizes, int n_in,
                              void* d_out, int out_size, void* d_ws, size_t ws_size,
                              hipStream_t stream) {
    const float* x            = (const float*)d_in[0];
    const float* logit_thresh = (const float*)d_in[1];

    float* smooth = (float*)d_out;                          // first output, ROWS*COLS f32
    float* mask   = (float*)d_out + (long long)ROWS * COLS; // second output, ROWS*COLS f32

    const long long n_elem   = (long long)ROWS * COLS;      // 33,554,432
    const long long n_thread = n_elem / 4;                  // 8,388,608
    const int block = 256;
    const int grid  = (int)(n_thread / block);              // 32,768

    peak_extract_kernel<<<grid, block, 0, stream>>>(x, logit_thresh, smooth, mask);
}